// Round 4
// baseline (237.890 us; speedup 1.0000x reference)
//
#include <hip/hip_runtime.h>

// MACE symmetric contraction (corr-3), N=2048, NL=16, C=128, E=10, P3=23, P2=4, P1=1.
// out[n,c] = sum_{a<=b<=i} A3[t,tri,c] x_a x_b x_i + sum_{a<=b} A2[t,pr,c] x_a x_b
//          + sum_a A1[t,a,c] x_a,  A3 = U3sym @ W3[t] (t = atom type).
// R4: Horner form (1 FMA/atom/triple). GG=4 atoms/thread-column, 256-thr blocks
// covering 2 group records (halves share coefficient cache lines). Register
// control via amdgpu_waves_per_eu(4) -> 128-VGPR cap, no spill (R3's
// __launch_bounds__(128,3) resolved to an 84-reg cap and spilled 165MB/way).

constexpr int NL = 16;
constexpr int CC = 128;
constexpr int EE = 10;
constexpr int P3 = 23;
constexpr int P2 = 4;
constexpr int NTRI = 816;   // C(18,3): a<=b<=i from 16
constexpr int NPAIR = 136;  // C(17,2): a<=b from 16
constexpr int GG = 4;       // atoms per group record
constexpr int GPB = 2;      // group records per 256-thread block

constexpr int pairsBefore(int a) {
    int s = 0;
    for (int x = 0; x < a; x++) s += NL - x;
    return s;
}
constexpr int trisBefore(int a) {
    int s = 0;
    for (int x = 0; x < a; x++) s += (NL - x) * (NL - x + 1) / 2;
    return s;
}
// split boundaries a in [0,2),[2,4),[4,8),[8,16): tri counts 256/196/244/120
static_assert(trisBefore(2) % 4 == 0 && trisBefore(4) % 4 == 0 && trisBefore(8) % 4 == 0, "");

// ---------------- symmetrize U3/U2 + zero out/counts ----------------
__global__ void k_symU(const float* __restrict__ U3, const float* __restrict__ U2,
                       float* __restrict__ U3s, float* __restrict__ U2s,
                       float* __restrict__ out, int out_n, int* __restrict__ counts) {
    int gtid = blockIdx.x * blockDim.x + threadIdx.x;
    int nthreads = gridDim.x * blockDim.x;
    if (gtid < 16) counts[gtid] = 0;
    for (int idx = gtid; idx < out_n; idx += nthreads) out[idx] = 0.f;
    int idx = gtid;
    if (idx < NTRI * P3) {
        int tri = idx / P3, k = idx % P3;
        int rem = tri, a = 0;
        while (rem >= (NL - a) * (NL - a + 1) / 2) { rem -= (NL - a) * (NL - a + 1) / 2; a++; }
        int b = a;
        while (rem >= NL - b) { rem -= NL - b; b++; }
        int i = b + rem;
        auto u = [&](int p, int q, int r) { return U3[((p * NL + q) * NL + r) * P3 + k]; };
        float s = u(a,b,i) + u(a,i,b) + u(b,a,i) + u(b,i,a) + u(i,a,b) + u(i,b,a);
        int m = (a == b && b == i) ? 6 : ((a == b || b == i) ? 2 : 1);
        U3s[idx] = s / (float)m;
    } else if (idx < NTRI * P3 + NPAIR * P2) {
        int j = idx - NTRI * P3;
        int pr = j / P2, k = j % P2;
        int rem = pr, a = 0;
        while (rem >= NL - a) { rem -= NL - a; a++; }
        int b = a + rem;
        float s = U2[(a * NL + b) * P2 + k];
        if (a != b) s += U2[(b * NL + a) * P2 + k];
        U2s[pr * P2 + k] = s;
    }
}

// ---------------- per-type tables, LDS-staged ----------------
// A3: [t][tri/4][c][4] (float4 of 4 consecutive tri per thread)
// A2: [t][pr][c] scalar; A1: [t][a][c]
__global__ __launch_bounds__(256) void k_buildA(const float* __restrict__ U3s,
                                                const float* __restrict__ U2s,
                                                const float* __restrict__ U1,
                                                const float* __restrict__ W3,
                                                const float* __restrict__ W2,
                                                const float* __restrict__ W1,
                                                float* __restrict__ A3, float* __restrict__ A2,
                                                float* __restrict__ A1) {
    int blk = blockIdx.x;
    int tid = threadIdx.x;
    if (blk < EE * 8) {
        int t = blk / 8, chunk = blk % 8;  // 102 tris per chunk
        __shared__ float W3s[P3 * CC];
        __shared__ float U3c[102 * P3];
        for (int idx = tid; idx < P3 * CC; idx += 256) W3s[idx] = W3[t * P3 * CC + idx];
        for (int idx = tid; idx < 102 * P3; idx += 256) U3c[idx] = U3s[chunk * 102 * P3 + idx];
        __syncthreads();
        int c = tid & 127, h = tid >> 7;
        for (int j = 0; j < 51; j++) {
            int tsub = h * 51 + j;
            int tri = chunk * 102 + tsub;
            float s = 0.f;
            #pragma unroll
            for (int k = 0; k < P3; k++) s += U3c[tsub * P3 + k] * W3s[k * CC + c];
            A3[(((size_t)t * (NTRI / 4) + (tri >> 2)) * CC + c) * 4 + (tri & 3)] = s;
        }
    } else {
        int t = blk - EE * 8;
        __shared__ float W2s[P2 * CC];
        __shared__ float U2c[NPAIR * P2];
        for (int idx = tid; idx < P2 * CC; idx += 256) W2s[idx] = W2[t * P2 * CC + idx];
        for (int idx = tid; idx < NPAIR * P2; idx += 256) U2c[idx] = U2s[idx];
        __syncthreads();
        int c = tid & 127, h = tid >> 7;
        for (int j = 0; j < NPAIR / 2; j++) {
            int pr = h * (NPAIR / 2) + j;
            float s = 0.f;
            #pragma unroll
            for (int k = 0; k < P2; k++) s += U2c[pr * P2 + k] * W2s[k * CC + c];
            A2[((size_t)t * NPAIR + pr) * CC + c] = s;
        }
        if (h == 0)
            for (int a = 0; a < NL; a++)
                A1[((size_t)t * NL + a) * CC + c] = U1[a] * W1[t * CC + c];
    }
}

// ---------------- bucket atoms by type; build GG-atom groups ----------------
__global__ void k_bucket(const int* __restrict__ types, int* counts, int* buckets, int N) {
    int n = blockIdx.x * blockDim.x + threadIdx.x;
    if (n < N) {
        int t = types[n];
        int pos = atomicAdd(&counts[t], 1);
        buckets[t * N + pos] = n;
    }
}

__global__ void k_groups(const int* __restrict__ counts, const int* __restrict__ buckets,
                         int* __restrict__ groups, int* __restrict__ ngroups, int N) {
    __shared__ int goff[EE + 1];
    if (threadIdx.x == 0) {
        int off = 0;
        for (int t = 0; t < EE; t++) { goff[t] = off; off += (counts[t] + GG - 1) / GG; }
        goff[EE] = off;
        *ngroups = off;
    }
    __syncthreads();
    for (int t = 0; t < EE; t++) {
        int cnt = counts[t];
        int ng = (cnt + GG - 1) / GG;
        for (int g = threadIdx.x; g < ng; g += blockDim.x) {
            int* gr = &groups[(goff[t] + g) * 8];
            int nv = cnt - g * GG; if (nv > GG) nv = GG;
            gr[0] = t;
            gr[5] = nv;
            for (int j = 0; j < GG; j++) {
                int jj = j < nv ? j : nv - 1;
                gr[1 + j] = buckets[t * N + g * GG + jj];
            }
        }
    }
}

// ---------------- main: Horner-form cubic evaluation ----------------
template <int A0, int A1v, bool LIN>
__device__ __forceinline__ void run_split(const float* __restrict__ x,
                                          const float4* __restrict__ a3v,
                                          const float* __restrict__ a2p,
                                          const float* __restrict__ a1p,
                                          const int (&na)[GG], int c, float (&acc)[GG]) {
    float xv[GG][NL];  // only [A0..NL) used unless LIN
    constexpr int L0 = LIN ? 0 : A0;
    #pragma unroll
    for (int g = 0; g < GG; g++)
        #pragma unroll
        for (int i = L0; i < NL; i++)
            xv[g][i] = x[((size_t)na[g] * NL + i) * CC + c];

    if (LIN) {
        #pragma unroll
        for (int a = 0; a < NL; a++) {
            float w = a1p[a * CC];
            #pragma unroll
            for (int g = 0; g < GG; g++) acc[g] += w * xv[g][a];
        }
    }

    float4 w4 = {0.f, 0.f, 0.f, 0.f};
    int tri = trisBefore(A0), pr = pairsBefore(A0);
    #pragma unroll
    for (int a = A0; a < A1v; a++) {
        float s[GG];
        #pragma unroll
        for (int g = 0; g < GG; g++) s[g] = 0.f;
        #pragma unroll
        for (int b = a; b < NL; b++) {
            float w2 = a2p[(size_t)pr * CC]; pr++;
            float r[GG];
            #pragma unroll
            for (int g = 0; g < GG; g++) r[g] = w2;
            #pragma unroll
            for (int i = b; i < NL; i++) {
                if ((tri & 3) == 0) w4 = a3v[(size_t)(tri >> 2) * CC];
                int rr = tri & 3;
                float w3 = (rr == 0) ? w4.x : (rr == 1) ? w4.y : (rr == 2) ? w4.z : w4.w;
                tri++;
                #pragma unroll
                for (int g = 0; g < GG; g++) r[g] += w3 * xv[g][i];
            }
            #pragma unroll
            for (int g = 0; g < GG; g++) s[g] += xv[g][b] * r[g];
        }
        #pragma unroll
        for (int g = 0; g < GG; g++) acc[g] += xv[g][a] * s[g];
    }
}

__global__ __launch_bounds__(GPB * CC) __attribute__((amdgpu_waves_per_eu(4)))
void k_main(const float* __restrict__ x,
            const float* __restrict__ A3,
            const float* __restrict__ A2,
            const float* __restrict__ A1,
            const int* __restrict__ groups,
            const int* __restrict__ ngroups,
            float* __restrict__ out) {
    int sub = threadIdx.x >> 7;       // which group record in this block
    int c = threadIdx.x & (CC - 1);   // channel
    int gidx = blockIdx.x * GPB + sub;
    if (gidx >= *ngroups) return;     // no barriers below -> safe divergence
    const int* gr = groups + gidx * 8;
    int t = gr[0];
    int nvalid = gr[5];

    int na[GG];
    #pragma unroll
    for (int g = 0; g < GG; g++) na[g] = gr[1 + g];

    const float4* a3v = (const float4*)A3 + (size_t)t * (NTRI / 4) * CC + c;
    const float* a2p = A2 + (size_t)t * NPAIR * CC + c;
    const float* a1p = A1 + (size_t)t * NL * CC + c;

    float acc[GG] = {0.f, 0.f, 0.f, 0.f};
    switch (blockIdx.y) {
        case 0: run_split<0, 2, true >(x, a3v, a2p, a1p, na, c, acc); break;
        case 1: run_split<2, 4, false>(x, a3v, a2p, a1p, na, c, acc); break;
        case 2: run_split<4, 8, false>(x, a3v, a2p, a1p, na, c, acc); break;
        default: run_split<8, 16, false>(x, a3v, a2p, a1p, na, c, acc); break;
    }

    #pragma unroll
    for (int g = 0; g < GG; g++)
        if (g < nvalid) atomicAdd(&out[(size_t)na[g] * CC + c], acc[g]);
}

extern "C" void kernel_launch(void* const* d_in, const int* in_sizes, int n_in,
                              void* d_out, int out_size, void* d_ws, size_t ws_size,
                              hipStream_t stream) {
    const float* x   = (const float*)d_in[0];
    const int* types = (const int*)d_in[1];
    const float* U3  = (const float*)d_in[2];
    const float* U2  = (const float*)d_in[3];
    const float* U1  = (const float*)d_in[4];
    const float* W3  = (const float*)d_in[5];
    const float* W2  = (const float*)d_in[6];
    const float* W1  = (const float*)d_in[7];
    float* out = (float*)d_out;
    int N = in_sizes[1];  // atom count (2048)

    int ngmax = (N + GG - 1) / GG + EE;  // upper bound on group count

    float* ws   = (float*)d_ws;
    float* U3s  = ws;                           // NTRI*P3
    float* U2s  = U3s + NTRI * P3;              // NPAIR*P2
    float* A3   = U2s + NPAIR * P2;             // EE*NTRI*CC (x4 interleaved)
    float* A2   = A3 + (size_t)EE * NTRI * CC;  // EE*NPAIR*CC
    float* A1   = A2 + (size_t)EE * NPAIR * CC; // EE*NL*CC
    int* counts  = (int*)(A1 + (size_t)EE * NL * CC);  // 16
    int* buckets = counts + 16;                 // EE*N
    int* groups  = buckets + (size_t)EE * N;    // ngmax*8
    int* ngroups = groups + (size_t)ngmax * 8;

    hipLaunchKernelGGL(k_symU, dim3(76), dim3(256), 0, stream,
                       U3, U2, U3s, U2s, out, out_size, counts);
    hipLaunchKernelGGL(k_buildA, dim3(EE * 8 + EE), dim3(256), 0, stream,
                       U3s, U2s, U1, W3, W2, W1, A3, A2, A1);
    hipLaunchKernelGGL(k_bucket, dim3((N + 255) / 256), dim3(256), 0, stream,
                       types, counts, buckets, N);
    hipLaunchKernelGGL(k_groups, dim3(1), dim3(256), 0, stream,
                       counts, buckets, groups, ngroups, N);
    hipLaunchKernelGGL(k_main, dim3((ngmax + GPB - 1) / GPB, 4), dim3(GPB * CC), 0, stream,
                       x, A3, A2, A1, groups, ngroups, out);
}

// Round 5
// 132.279 us; speedup vs baseline: 1.7984x; 1.7984x over previous
//
#include <hip/hip_runtime.h>

// MACE symmetric contraction (corr-3), N=2048, NL=16, C=128, E=10, P3=23, P2=4, P1=1.
// out[n,c] = sum_{a<=b<=i} A3[t,tri,c] x_a x_b x_i + sum_{a<=b} A2[t,pr,c] x_a x_b
//          + sum_a A1[t,a,c] x_a,  A3 = U3sym @ W3[t] (t = atom type).
// R5: Horner form (1 FMA/atom/triple). GG=2 atoms per 128-thread block so the
// live set (~60 VGPR) fits ANY budget the allocator picks. NO occupancy
// attributes: R3's __launch_bounds__(128,3)->84 regs and R4's
// waves_per_eu(4)->64 regs both forced 165-230MB/way scratch spills; the
// uncapped allocator (R1) chose 256 regs. 4-way a-split, ~4120 blocks.

constexpr int NL = 16;
constexpr int CC = 128;
constexpr int EE = 10;
constexpr int P3 = 23;
constexpr int P2 = 4;
constexpr int NTRI = 816;   // C(18,3): a<=b<=i from 16
constexpr int NPAIR = 136;  // C(17,2): a<=b from 16
constexpr int GG = 2;       // atoms per group record (record = 4 ints)

constexpr int pairsBefore(int a) {
    int s = 0;
    for (int x = 0; x < a; x++) s += NL - x;
    return s;
}
constexpr int trisBefore(int a) {
    int s = 0;
    for (int x = 0; x < a; x++) s += (NL - x) * (NL - x + 1) / 2;
    return s;
}
// split boundaries a in [0,2),[2,4),[4,8),[8,16): tri counts 256/196/244/120
static_assert(trisBefore(2) % 4 == 0 && trisBefore(4) % 4 == 0 && trisBefore(8) % 4 == 0, "");

// ---------------- symmetrize U3/U2 + zero out/counts ----------------
__global__ void k_symU(const float* __restrict__ U3, const float* __restrict__ U2,
                       float* __restrict__ U3s, float* __restrict__ U2s,
                       float* __restrict__ out, int out_n, int* __restrict__ counts) {
    int gtid = blockIdx.x * blockDim.x + threadIdx.x;
    int nthreads = gridDim.x * blockDim.x;
    if (gtid < 16) counts[gtid] = 0;
    for (int idx = gtid; idx < out_n; idx += nthreads) out[idx] = 0.f;
    int idx = gtid;
    if (idx < NTRI * P3) {
        int tri = idx / P3, k = idx % P3;
        int rem = tri, a = 0;
        while (rem >= (NL - a) * (NL - a + 1) / 2) { rem -= (NL - a) * (NL - a + 1) / 2; a++; }
        int b = a;
        while (rem >= NL - b) { rem -= NL - b; b++; }
        int i = b + rem;
        auto u = [&](int p, int q, int r) { return U3[((p * NL + q) * NL + r) * P3 + k]; };
        float s = u(a,b,i) + u(a,i,b) + u(b,a,i) + u(b,i,a) + u(i,a,b) + u(i,b,a);
        int m = (a == b && b == i) ? 6 : ((a == b || b == i) ? 2 : 1);
        U3s[idx] = s / (float)m;
    } else if (idx < NTRI * P3 + NPAIR * P2) {
        int j = idx - NTRI * P3;
        int pr = j / P2, k = j % P2;
        int rem = pr, a = 0;
        while (rem >= NL - a) { rem -= NL - a; a++; }
        int b = a + rem;
        float s = U2[(a * NL + b) * P2 + k];
        if (a != b) s += U2[(b * NL + a) * P2 + k];
        U2s[pr * P2 + k] = s;
    }
}

// ---------------- per-type tables, LDS-staged ----------------
// A3: [t][tri/4][c][4] (float4 of 4 consecutive tri per thread)
// A2: [t][pr][c] scalar; A1: [t][a][c]
__global__ __launch_bounds__(256) void k_buildA(const float* __restrict__ U3s,
                                                const float* __restrict__ U2s,
                                                const float* __restrict__ U1,
                                                const float* __restrict__ W3,
                                                const float* __restrict__ W2,
                                                const float* __restrict__ W1,
                                                float* __restrict__ A3, float* __restrict__ A2,
                                                float* __restrict__ A1) {
    int blk = blockIdx.x;
    int tid = threadIdx.x;
    if (blk < EE * 8) {
        int t = blk / 8, chunk = blk % 8;  // 102 tris per chunk
        __shared__ float W3s[P3 * CC];
        __shared__ float U3c[102 * P3];
        for (int idx = tid; idx < P3 * CC; idx += 256) W3s[idx] = W3[t * P3 * CC + idx];
        for (int idx = tid; idx < 102 * P3; idx += 256) U3c[idx] = U3s[chunk * 102 * P3 + idx];
        __syncthreads();
        int c = tid & 127, h = tid >> 7;
        for (int j = 0; j < 51; j++) {
            int tsub = h * 51 + j;
            int tri = chunk * 102 + tsub;
            float s = 0.f;
            #pragma unroll
            for (int k = 0; k < P3; k++) s += U3c[tsub * P3 + k] * W3s[k * CC + c];
            A3[(((size_t)t * (NTRI / 4) + (tri >> 2)) * CC + c) * 4 + (tri & 3)] = s;
        }
    } else {
        int t = blk - EE * 8;
        __shared__ float W2s[P2 * CC];
        __shared__ float U2c[NPAIR * P2];
        for (int idx = tid; idx < P2 * CC; idx += 256) W2s[idx] = W2[t * P2 * CC + idx];
        for (int idx = tid; idx < NPAIR * P2; idx += 256) U2c[idx] = U2s[idx];
        __syncthreads();
        int c = tid & 127, h = tid >> 7;
        for (int j = 0; j < NPAIR / 2; j++) {
            int pr = h * (NPAIR / 2) + j;
            float s = 0.f;
            #pragma unroll
            for (int k = 0; k < P2; k++) s += U2c[pr * P2 + k] * W2s[k * CC + c];
            A2[((size_t)t * NPAIR + pr) * CC + c] = s;
        }
        if (h == 0)
            for (int a = 0; a < NL; a++)
                A1[((size_t)t * NL + a) * CC + c] = U1[a] * W1[t * CC + c];
    }
}

// ---------------- bucket atoms by type; build GG-atom groups ----------------
__global__ void k_bucket(const int* __restrict__ types, int* counts, int* buckets, int N) {
    int n = blockIdx.x * blockDim.x + threadIdx.x;
    if (n < N) {
        int t = types[n];
        int pos = atomicAdd(&counts[t], 1);
        buckets[t * N + pos] = n;
    }
}

__global__ void k_groups(const int* __restrict__ counts, const int* __restrict__ buckets,
                         int* __restrict__ groups, int* __restrict__ ngroups, int N) {
    __shared__ int goff[EE + 1];
    if (threadIdx.x == 0) {
        int off = 0;
        for (int t = 0; t < EE; t++) { goff[t] = off; off += (counts[t] + GG - 1) / GG; }
        goff[EE] = off;
        *ngroups = off;
    }
    __syncthreads();
    for (int t = 0; t < EE; t++) {
        int cnt = counts[t];
        int ng = (cnt + GG - 1) / GG;
        for (int g = threadIdx.x; g < ng; g += blockDim.x) {
            int* gr = &groups[(goff[t] + g) * 4];
            int nv = cnt - g * GG; if (nv > GG) nv = GG;
            gr[0] = t;
            gr[3] = nv;
            for (int j = 0; j < GG; j++) {
                int jj = j < nv ? j : nv - 1;
                gr[1 + j] = buckets[t * N + g * GG + jj];
            }
        }
    }
}

// ---------------- main: Horner-form cubic evaluation ----------------
template <int A0, int A1v, bool LIN>
__device__ __forceinline__ void run_split(const float* __restrict__ x,
                                          const float4* __restrict__ a3v,
                                          const float* __restrict__ a2p,
                                          const float* __restrict__ a1p,
                                          const int (&na)[GG], int c, float (&acc)[GG]) {
    float xv[GG][NL];  // only [A0..NL) used unless LIN
    constexpr int L0 = LIN ? 0 : A0;
    #pragma unroll
    for (int g = 0; g < GG; g++)
        #pragma unroll
        for (int i = L0; i < NL; i++)
            xv[g][i] = x[((size_t)na[g] * NL + i) * CC + c];

    if (LIN) {
        #pragma unroll
        for (int a = 0; a < NL; a++) {
            float w = a1p[a * CC];
            #pragma unroll
            for (int g = 0; g < GG; g++) acc[g] += w * xv[g][a];
        }
    }

    float4 w4 = {0.f, 0.f, 0.f, 0.f};
    int tri = trisBefore(A0), pr = pairsBefore(A0);
    #pragma unroll
    for (int a = A0; a < A1v; a++) {
        float s[GG];
        #pragma unroll
        for (int g = 0; g < GG; g++) s[g] = 0.f;
        #pragma unroll
        for (int b = a; b < NL; b++) {
            float w2 = a2p[(size_t)pr * CC]; pr++;
            float r[GG];
            #pragma unroll
            for (int g = 0; g < GG; g++) r[g] = w2;
            #pragma unroll
            for (int i = b; i < NL; i++) {
                if ((tri & 3) == 0) w4 = a3v[(size_t)(tri >> 2) * CC];
                int rr = tri & 3;
                float w3 = (rr == 0) ? w4.x : (rr == 1) ? w4.y : (rr == 2) ? w4.z : w4.w;
                tri++;
                #pragma unroll
                for (int g = 0; g < GG; g++) r[g] += w3 * xv[g][i];
            }
            #pragma unroll
            for (int g = 0; g < GG; g++) s[g] += xv[g][b] * r[g];
        }
        #pragma unroll
        for (int g = 0; g < GG; g++) acc[g] += xv[g][a] * s[g];
    }
}

__global__ __launch_bounds__(CC) void k_main(const float* __restrict__ x,
                                             const float* __restrict__ A3,
                                             const float* __restrict__ A2,
                                             const float* __restrict__ A1,
                                             const int* __restrict__ groups,
                                             const int* __restrict__ ngroups,
                                             float* __restrict__ out) {
    int gidx = blockIdx.x;
    if (gidx >= *ngroups) return;
    const int* gr = groups + gidx * 4;
    int t = gr[0];
    int nvalid = gr[3];
    int c = threadIdx.x;

    int na[GG];
    #pragma unroll
    for (int g = 0; g < GG; g++) na[g] = gr[1 + g];

    const float4* a3v = (const float4*)A3 + (size_t)t * (NTRI / 4) * CC + c;
    const float* a2p = A2 + (size_t)t * NPAIR * CC + c;
    const float* a1p = A1 + (size_t)t * NL * CC + c;

    float acc[GG] = {0.f, 0.f};
    switch (blockIdx.y) {
        case 0: run_split<0, 2, true >(x, a3v, a2p, a1p, na, c, acc); break;
        case 1: run_split<2, 4, false>(x, a3v, a2p, a1p, na, c, acc); break;
        case 2: run_split<4, 8, false>(x, a3v, a2p, a1p, na, c, acc); break;
        default: run_split<8, 16, false>(x, a3v, a2p, a1p, na, c, acc); break;
    }

    #pragma unroll
    for (int g = 0; g < GG; g++)
        if (g < nvalid) atomicAdd(&out[(size_t)na[g] * CC + c], acc[g]);
}

extern "C" void kernel_launch(void* const* d_in, const int* in_sizes, int n_in,
                              void* d_out, int out_size, void* d_ws, size_t ws_size,
                              hipStream_t stream) {
    const float* x   = (const float*)d_in[0];
    const int* types = (const int*)d_in[1];
    const float* U3  = (const float*)d_in[2];
    const float* U2  = (const float*)d_in[3];
    const float* U1  = (const float*)d_in[4];
    const float* W3  = (const float*)d_in[5];
    const float* W2  = (const float*)d_in[6];
    const float* W1  = (const float*)d_in[7];
    float* out = (float*)d_out;
    int N = in_sizes[1];  // atom count (2048)

    int ngmax = (N + GG - 1) / GG + EE;  // upper bound on group count

    float* ws   = (float*)d_ws;
    float* U3s  = ws;                           // NTRI*P3
    float* U2s  = U3s + NTRI * P3;              // NPAIR*P2
    float* A3   = U2s + NPAIR * P2;             // EE*NTRI*CC (x4 interleaved)
    float* A2   = A3 + (size_t)EE * NTRI * CC;  // EE*NPAIR*CC
    float* A1   = A2 + (size_t)EE * NPAIR * CC; // EE*NL*CC
    int* counts  = (int*)(A1 + (size_t)EE * NL * CC);  // 16
    int* buckets = counts + 16;                 // EE*N
    int* groups  = buckets + (size_t)EE * N;    // ngmax*4
    int* ngroups = groups + (size_t)ngmax * 4;

    hipLaunchKernelGGL(k_symU, dim3(76), dim3(256), 0, stream,
                       U3, U2, U3s, U2s, out, out_size, counts);
    hipLaunchKernelGGL(k_buildA, dim3(EE * 8 + EE), dim3(256), 0, stream,
                       U3s, U2s, U1, W3, W2, W1, A3, A2, A1);
    hipLaunchKernelGGL(k_bucket, dim3((N + 255) / 256), dim3(256), 0, stream,
                       types, counts, buckets, N);
    hipLaunchKernelGGL(k_groups, dim3(1), dim3(256), 0, stream,
                       counts, buckets, groups, ngroups, N);
    hipLaunchKernelGGL(k_main, dim3(ngmax, 4), dim3(CC), 0, stream,
                       x, A3, A2, A1, groups, ngroups, out);
}